// Round 17
// baseline (196.762 us; speedup 1.0000x reference)
//
#include <hip/hip_runtime.h>

#define NPIX   65536          // B*H*W
#define CCH    64
#define KCODE  1024
#define HW     4096
#define Q_ELEMS 4194304
#define LOSS0_OFF 4194304
#define LOSS1_OFF 4194305
#define IDX_OFF   4194306
#define PTILE  16             // pixels per block
#define PH     8              // pixels per pass (R17 pixel-split)

// numpy pairwise_sum middle branch for n=64 on squares (bit-exact np.sum(x*x))
template <typename F>
__device__ __forceinline__ float np_pairwise64_sq(F v) {
    float r[8];
#pragma unroll
    for (int j = 0; j < 8; ++j) r[j] = __fmul_rn(v(j), v(j));
#pragma unroll
    for (int i = 8; i < 64; i += 8) {
#pragma unroll
        for (int j = 0; j < 8; ++j)
            r[j] = __fadd_rn(r[j], __fmul_rn(v(i + j), v(i + j)));
    }
    return __fadd_rn(
        __fadd_rn(__fadd_rn(r[0], r[1]), __fadd_rn(r[2], r[3])),
        __fadd_rn(__fadd_rn(r[4], r[5]), __fadd_rn(r[6], r[7])));
}

// prep v2 (verified absmax 0): LDS-tile transpose, coalesced on both sides.
__global__ void prep_kernel(const float* __restrict__ emb,
                            float* __restrict__ se, float* __restrict__ et,
                            float* __restrict__ out) {
    __shared__ float s_e[64][65];                      // +pad: conflict-free both axes
    const int t  = threadIdx.x;
    const int k0 = blockIdx.x << 6;
#pragma unroll
    for (int i = 0; i < 4; ++i) {
        const int q = (i << 8) + t;                    // float4 index 0..1023
        const float4 v = reinterpret_cast<const float4*>(emb + ((size_t)k0 << 6))[q];
        const int r = q >> 4, c4 = (q & 15) << 2;
        s_e[r][c4] = v.x; s_e[r][c4 + 1] = v.y; s_e[r][c4 + 2] = v.z; s_e[r][c4 + 3] = v.w;
    }
    __syncthreads();
    if (t < 64)
        se[k0 + t] = np_pairwise64_sq([&](int i) { return s_e[t][i]; });
#pragma unroll
    for (int i = 0; i < 16; ++i) {
        const int n = (i << 8) + t;                    // 0..4095
        const int c = n >> 6, kk = n & 63;
        et[((size_t)c << 10) + k0 + kk] = s_e[kk][c];  // wave: 256B contiguous
    }
    if ((blockIdx.x | t) == 0) { out[LOSS0_OFF] = 0.f; out[LOSS1_OFF] = 0.f; }
}

// main: R17 pixel-split. R16 established: R8 holds ~85 live values (64 acc +
// 16 szz + ev/addr) in 52 arch VGPRs => ~20 AGPR-parked, whose accvgpr
// read/write moves add ~40 VALU slots per c-iter (= the measured 83us issue
// vs the 54.6us FMA floor). Fix: TWO passes over the full c-loop, 8 pixels
// each. Hot-loop live = acc 32 + ev 4 + addr ~4 < 64-VGPR cap => no parking.
// best[] handed off to LDS at the END of each pass (R11's failure was best
// staying live across passes); szz/se read only in pass tails. ev re-reads
// (2x et traffic) are L2-absorbed -> FETCH flat. All FMA chains, d formula,
// fold order bit-identical to R8 -> absmax 0.
__launch_bounds__(256, 4)
__global__ void vq_kernel(const float* __restrict__ z,
                          const float* __restrict__ emb,
                          const float* __restrict__ se,
                          const float* __restrict__ et,
                          float* __restrict__ out) {
    __shared__ float s_szz[PTILE];
    __shared__ unsigned long long s_cand[PTILE][129];  // halved via shfl pre-reduce; +pad
    __shared__ unsigned long long s_part[PTILE][16];
    __shared__ unsigned int s_k[PTILE];
    __shared__ float s_red[4];

    const int t    = threadIdx.x;
    const int lane = t & 63;
    const int wave = t >> 6;
    const int pg0  = blockIdx.x * PTILE;
    const int b    = pg0 >> 12;
    const int hw0  = pg0 & 4095;
    const float* zb = z + (size_t)b * CCH * HW + hw0;  // zb[c*HW + p], wave-uniform

    // szz for the block's 16 pixels (np order), lanes 0..15 of wave 0
    if (t < PTILE)
        s_szz[t] = np_pairwise64_sq([&](int i) { return zb[(size_t)i * HW + t]; });
    __syncthreads();

    const float* ecol = et + (t << 2);                 // 4 consecutive codes

#pragma unroll 1
    for (int h = 0; h < 2; ++h) {                      // pixel halves: 0-7, 8-15
        const int p0 = h << 3;

        // ---- accumulation: acc[j][p] = sum_c z[c][p0+p] * E^T[c][4t+j] ----
        float acc[4][PH];
#pragma unroll
        for (int j = 0; j < 4; ++j)
#pragma unroll
            for (int p = 0; p < PH; ++p) acc[j][p] = 0.f;

#pragma unroll 4
        for (int c = 0; c < CCH; ++c) {
            const float4 evv = *reinterpret_cast<const float4*>(ecol + (c << 10));
            const float ev[4] = {evv.x, evv.y, evv.z, evv.w};
            float zrow[PH];                             // uniform -> s_load_dwordx8
#pragma unroll
            for (int p = 0; p < PH; ++p) zrow[p] = zb[(size_t)c * HW + p0 + p];
#pragma unroll
            for (int j = 0; j < 4; ++j)
#pragma unroll
                for (int p = 0; p < PH; ++p)
                    acc[j][p] = __builtin_fmaf(zrow[p], ev[j], acc[j][p]);  // same chain as R8
        }

        // ---- pass tail: distances + per-thread best for these 8 pixels ----
        float szzv[PH];
#pragma unroll
        for (int p = 0; p < PH; ++p) szzv[p] = s_szz[p0 + p];
        const float4 se4v = *reinterpret_cast<const float4*>(se + (t << 2));
        const float se4[4] = {se4v.x, se4v.y, se4v.z, se4v.w};

        unsigned long long best[PH];
#pragma unroll
        for (int p = 0; p < PH; ++p) best[p] = ~0ULL;

#pragma unroll
        for (int j = 0; j < 4; ++j) {
            const int kk = (t << 2) + j;
#pragma unroll
            for (int p = 0; p < PH; ++p) {
                // d = fl( fl(szz+se) - 2*dot )  (identical algebra to R8, absmax 0)
                float d = __fsub_rn(__fadd_rn(szzv[p], se4[j]),
                                    __fadd_rn(acc[j][p], acc[j][p]));
                unsigned long long cand =
                    ((unsigned long long)__float_as_uint(d) << 32) | (unsigned)kk;
                best[p] = cand < best[p] ? cand : best[p];  // d>0 -> bit-order == value-order
            }
        }

        // stage 1.5: one butterfly step in registers (exact: u64 min over same set),
        // then hand off to LDS so nothing stays live across the next pass
#pragma unroll
        for (int p = 0; p < PH; ++p) {
            unsigned long long o = __shfl_xor(best[p], 1, 64);
            best[p] = o < best[p] ? o : best[p];
        }
        if ((t & 1) == 0) {
#pragma unroll
            for (int p = 0; p < PH; ++p) s_cand[p0 + p][t >> 1] = best[p];
        }
    }
    __syncthreads();

    {   // stage 2: 256 threads, each folds 8 of the 128 candidates of pixel t&15
        const int p = t & 15, g = t >> 4;
        unsigned long long m = s_cand[p][(g << 3)];
#pragma unroll
        for (int u = 1; u < 8; ++u) {
            unsigned long long v = s_cand[p][(g << 3) + u];
            m = v < m ? v : m;
        }
        s_part[p][g] = m;
    }
    __syncthreads();

    if (t < PTILE) {   // stage 3: final per-pixel min; packed low bits = first-index k
        unsigned long long m = s_part[t][0];
#pragma unroll
        for (int g = 1; g < 16; ++g) {
            unsigned long long v = s_part[t][g];
            m = v < m ? v : m;
        }
        const unsigned int k = (unsigned int)m;
        s_k[t] = k;
        out[IDX_OFF + pg0 + t] = (float)k;
    }
    __syncthreads();

    // epilogue: thread t -> pixel p=t&15, channels c = (t>>4) + 16u
    float lsum = 0.f;
    {
        const int p = t & 15, g = t >> 4;
        const int k = (int)s_k[p];
#pragma unroll
        for (int u = 0; u < 4; ++u) {
            const int c = g + (u << 4);
            float e    = emb[(size_t)k * CCH + c];
            float zc   = zb[(size_t)c * HW + p];
            float diff = __fsub_rn(e, zc);               // STE rounding as in R8
            out[((size_t)(b * CCH + c)) * HW + hw0 + p] = __fadd_rn(zc, diff);
            lsum = __builtin_fmaf(diff, diff, lsum);
        }
    }
#pragma unroll
    for (int off = 32; off > 0; off >>= 1) lsum += __shfl_down(lsum, off, 64);
    if (lane == 0) s_red[wave] = lsum;
    __syncthreads();
    if (t == 0) {
        float v = (s_red[0] + s_red[1] + s_red[2] + s_red[3]) * (1.0f / (float)Q_ELEMS);
        atomicAdd(out + LOSS0_OFF, v);   // codebook_loss
        atomicAdd(out + LOSS1_OFF, v);   // commitment_loss (same forward value)
    }
}

extern "C" void kernel_launch(void* const* d_in, const int* in_sizes, int n_in,
                              void* d_out, int out_size, void* d_ws, size_t ws_size,
                              hipStream_t stream) {
    const float* z   = (const float*)d_in[0];
    const float* emb = (const float*)d_in[1];
    float* out = (float*)d_out;
    float* se  = (float*)d_ws;                 // 1024 floats
    float* et  = se + KCODE;                   // 65536 floats (E^T)

    prep_kernel<<<dim3(16), dim3(256), 0, stream>>>(emb, se, et, out);
    vq_kernel<<<dim3(NPIX / PTILE), dim3(256), 0, stream>>>(z, emb, se, et, out);
}